// Round 3
// baseline (108.992 us; speedup 1.0000x reference)
//
#include <hip/hip_runtime.h>

#define R 192
#define BATCH 1024
#define RCH 8                   // rooms per transpose block

// ws layout:
//   float ws[0..3]        : accumulators (pos_mse, size_mse, overlap, adj)
//   u32   at +16 B        : adjacency bitmask [R][6], triu-baked (bit j iff j>i && adj>0)
//   float4 at +8192 B     : roomT [R][BATCH] = (x,y,w,h), 3 MB, L2-resident
#define MASK_OFF_W 4
#define ROOMT_OFF_B 8192

// Kernel 1: zero accumulators + build triu-baked adjacency bitmask via ballot.
__global__ __launch_bounds__(256) void prep_kernel(
    const int* __restrict__ adj, float* __restrict__ ws)
{
    unsigned int* bits = (unsigned int*)(ws + MASK_OFF_W);
    const int e = blockIdx.x * 256 + threadIdx.x;   // 0 .. R*R-1
    if (e < 4) ws[e] = 0.0f;
    if (e >= R * R) return;
    const int i = e / R;
    const int j = e - i * R;
    const unsigned long long m = __ballot((adj[e] > 0) && (j > i));
    const int lane = e & 63;
    if (lane == 0)  bits[e >> 5] = (unsigned int)m;          // e>>5 == i*6 + j/32
    if (lane == 32) bits[e >> 5] = (unsigned int)(m >> 32);
}

// Kernel 2: transpose [B,R,2]x2 -> roomT [R][B] float4, fusing the two MSE sums.
// Lanes = consecutive b: writes perfectly coalesced; reads L1-amortized over the r-loop.
__global__ __launch_bounds__(256) void transpose_mse_kernel(
    const float* __restrict__ pos, const float* __restrict__ siz,
    const float* __restrict__ tpos, const float* __restrict__ tsiz,
    float* __restrict__ ws)
{
    __shared__ float wsum[4][2];
    float4* roomT = (float4*)((char*)ws + ROOMT_OFF_B);
    const int tid = threadIdx.x;
    const int b   = blockIdx.x * 256 + tid;
    const int r0  = blockIdx.y * RCH;

    const float2* pb  = (const float2*)pos  + (size_t)b * R;
    const float2* sb  = (const float2*)siz  + (size_t)b * R;
    const float2* tpb = (const float2*)tpos + (size_t)b * R;
    const float2* tsb = (const float2*)tsiz + (size_t)b * R;

    float mp = 0.0f, ms = 0.0f;
    #pragma unroll
    for (int k = 0; k < RCH; ++k) {
        const int r = r0 + k;
        float2 p  = pb[r];
        float2 s  = sb[r];
        float2 tp = tpb[r];
        float2 ts = tsb[r];
        float dpx = p.x - tp.x, dpy = p.y - tp.y;
        float dsx = s.x - ts.x, dsy = s.y - ts.y;
        mp += dpx * dpx + dpy * dpy;
        ms += dsx * dsx + dsy * dsy;
        roomT[r * BATCH + b] = make_float4(p.x, p.y, s.x, s.y);
    }

    for (int off = 32; off > 0; off >>= 1) {
        mp += __shfl_down(mp, off);
        ms += __shfl_down(ms, off);
    }
    const int wid = tid >> 6, lane = tid & 63;
    if (lane == 0) { wsum[wid][0] = mp; wsum[wid][1] = ms; }
    __syncthreads();
    if (tid < 2) {
        float v = wsum[0][tid] + wsum[1][tid] + wsum[2][tid] + wsum[3][tid];
        atomicAdd(&ws[tid], v);
    }
}

// Kernel 3: pair loop, batch-on-lanes. Block = (b-group, i). j-loop is wave-uniform:
// adjacency bit is scalar (s_cbranch skips dist+sqrt for ~50% of j), hot-loop memory is
// one coalesced dwordx4 per j from L2-resident roomT. No LDS in the hot loop.
__global__ __launch_bounds__(256) void pairs_kernel(float* __restrict__ ws)
{
    __shared__ float wsum[4][2];
    const float4* __restrict__ roomT = (const float4*)((const char*)ws + ROOMT_OFF_B);
    const unsigned int* __restrict__ bits = (const unsigned int*)(ws + MASK_OFF_W);

    const int tid = threadIdx.x;
    const int b   = blockIdx.x * 256 + tid;
    const int i   = blockIdx.y;                 // 0 .. R-2

    const float4 ri = roomT[i * BATCH + b];
    const float xi  = ri.x, yi = ri.y;
    const float xiw = ri.x + ri.z;
    const float yih = ri.y + ri.w;
    const float cxi = fmaf(0.5f, ri.z, ri.x);
    const float cyi = fmaf(0.5f, ri.w, ri.y);
    const unsigned int* rowbits = bits + i * 6; // uniform -> scalar loads

    float ov = 0.0f, ad = 0.0f;
    for (int j = i + 1; j < R; ++j) {
        const float4 rj = roomT[j * BATCH + b];
        float ow = fminf(xiw, rj.x + rj.z) - fmaxf(xi, rj.x);
        float oh = fminf(yih, rj.y + rj.w) - fmaxf(yi, rj.y);
        ow = fmaxf(ow, 0.0f);
        oh = fmaxf(oh, 0.0f);
        ov += ow * oh;
        if ((rowbits[j >> 5] >> (j & 31)) & 1u) {   // wave-uniform branch
            float dx = cxi - fmaf(0.5f, rj.z, rj.x);
            float dy = cyi - fmaf(0.5f, rj.w, rj.y);
            ad += __builtin_amdgcn_sqrtf(fmaf(dx, dx, dy * dy));
        }
    }

    for (int off = 32; off > 0; off >>= 1) {
        ov += __shfl_down(ov, off);
        ad += __shfl_down(ad, off);
    }
    const int wid = tid >> 6, lane = tid & 63;
    if (lane == 0) { wsum[wid][0] = ov; wsum[wid][1] = ad; }
    __syncthreads();
    if (tid < 2) {
        float v = wsum[0][tid] + wsum[1][tid] + wsum[2][tid] + wsum[3][tid];
        atomicAdd(&ws[2 + tid], v);
    }
}

__global__ void finalize_kernel(const float* __restrict__ ws, float* __restrict__ out) {
    if (threadIdx.x == 0 && blockIdx.x == 0) {
        const float invN = 1.0f / (float)(BATCH * R * 2);
        const float invB = 1.0f / (float)BATCH;
        float pos_loss  = ws[0] * invN;
        float size_loss = ws[1] * invN;
        float overlap   = ws[2] * invB;
        float adjl      = ws[3] * invB;
        out[0] = pos_loss + size_loss + 0.5f * overlap + 0.3f * adjl;
        out[1] = pos_loss;
        out[2] = size_loss;
        out[3] = overlap;
        out[4] = adjl;
    }
}

extern "C" void kernel_launch(void* const* d_in, const int* in_sizes, int n_in,
                              void* d_out, int out_size, void* d_ws, size_t ws_size,
                              hipStream_t stream) {
    const float* pos  = (const float*)d_in[0];
    const float* siz  = (const float*)d_in[1];
    const float* tpos = (const float*)d_in[2];
    const float* tsiz = (const float*)d_in[3];
    const int*   adj  = (const int*)d_in[4];
    float* ws  = (float*)d_ws;
    float* out = (float*)d_out;

    hipLaunchKernelGGL(prep_kernel, dim3((R * R + 255) / 256), dim3(256), 0, stream,
                       adj, ws);
    hipLaunchKernelGGL(transpose_mse_kernel, dim3(BATCH / 256, R / RCH), dim3(256), 0, stream,
                       pos, siz, tpos, tsiz, ws);
    hipLaunchKernelGGL(pairs_kernel, dim3(BATCH / 256, R - 1), dim3(256), 0, stream, ws);
    hipLaunchKernelGGL(finalize_kernel, dim3(1), dim3(1), 0, stream, ws, out);
}